// Round 1
// baseline (777.693 us; speedup 1.0000x reference)
//
#include <hip/hip_runtime.h>
#include <hip/hip_bf16.h>

// Problem constants (fixed by reference)
#define T_TOTAL 786432
#define N_IN 50
#define K_FEAT 400
#define C_OUT 10
#define ROWS_PER_CHUNK 48                      // LCM(16,24): 2 pool segments
#define NCHUNKS (T_TOTAL / ROWS_PER_CHUNK)     // 16384
#define CHUNKS_PER_BLOCK 8
#define NBLOCKS (NCHUNKS / CHUNKS_PER_BLOCK)   // 2048
#define NTHREADS 320                           // 5 waves; 25 k-tiles / 5
#define XS_STRIDE 72                           // shorts; mult of 8 -> 16B-aligned rows, 2-way banks max

typedef __bf16 bfx8 __attribute__((ext_vector_type(8)));
typedef short  s16x8 __attribute__((ext_vector_type(8)));
typedef float  f32x4 __attribute__((ext_vector_type(4)));

static __device__ __forceinline__ short f2bf(float f) {
    // round-to-nearest-even fp32 -> bf16 bits (inputs are finite normals)
    union { float f; unsigned u; } v; v.f = f;
    unsigned r = v.u + 0x7fffu + ((v.u >> 16) & 1u);
    return (short)(r >> 16);
}

__global__ __launch_bounds__(NTHREADS) void classifier_kernel(
    const float* __restrict__ x, const float* __restrict__ W1,
    const float* __restrict__ W2, float* __restrict__ out)
{
    __shared__ short xs[ROWS_PER_CHUNK * XS_STRIDE];   // 6912 B bf16 x-tile
    __shared__ float pooled[2 * K_FEAT];               // 3.2 KB pooled sums
    __shared__ float w2s[C_OUT * K_FEAT];              // 16 KB W2

    const int tid  = threadIdx.x;
    const int wave = tid >> 6;      // 0..4
    const int lane = tid & 63;
    const int m16  = lane & 15;
    const int quad = lane >> 4;

    // W2 -> LDS once per block
    for (int i = tid; i < C_OUT * K_FEAT; i += NTHREADS) w2s[i] = W2[i];

    // B fragments (W1^T) once per wave into registers: k-tiles wave*5..wave*5+4.
    // B[k][n] layout: lane holds B[quad*8+j][m16] = W1[ktile*16+m16][quad*8+j]
    s16x8 bfrag[5][2];
    #pragma unroll
    for (int t = 0; t < 5; ++t) {
        const int kk = (wave * 5 + t) * 16 + m16;
        const float* w1row = W1 + kk * N_IN;
        #pragma unroll
        for (int s = 0; s < 2; ++s) {
            s16x8 f;
            #pragma unroll
            for (int j = 0; j < 8; ++j) {
                const int n = s * 32 + quad * 8 + j;
                f[j] = (n < N_IN) ? f2bf(w1row[n]) : (short)0;
            }
            bfrag[t][s] = f;
        }
    }

    for (int ciq = 0; ciq < CHUNKS_PER_BLOCK; ++ciq) {
        const int chunk = blockIdx.x * CHUNKS_PER_BLOCK + ciq;
        const int base  = chunk * (ROWS_PER_CHUNK * N_IN);  // < 2^26, int ok

        __syncthreads();  // previous iteration's pooled/xs readers done

        for (int i = tid; i < 2 * K_FEAT; i += NTHREADS) pooled[i] = 0.0f;
        // stage x chunk (contiguous 9600 B) as float2 -> packed bf16 pair
        for (int i = tid; i < (ROWS_PER_CHUNK * N_IN) / 2; i += NTHREADS) {
            const int r = i / 25;               // 25 float2 per row
            const int c = 2 * (i - r * 25);
            const float2 v = *(const float2*)(x + base + 2 * i);
            const int packed = (unsigned short)f2bf(v.x) |
                               ((unsigned)(unsigned short)f2bf(v.y) << 16);
            *(int*)&xs[r * XS_STRIDE + c] = packed;
        }
        // zero pad cols 50..63 (read by k-step 1)
        for (int i = tid; i < ROWS_PER_CHUNK * 14; i += NTHREADS) {
            const int r = i / 14, c = 50 + (i - r * 14);
            xs[r * XS_STRIDE + c] = 0;
        }
        __syncthreads();

        // 3 row-tiles of 16; per tile: 5 k-tiles x 2 k-steps of MFMA
        #pragma unroll
        for (int r = 0; r < 3; ++r) {
            const short* arow = &xs[(r * 16 + m16) * XS_STRIDE + quad * 8];
            const bfx8 a0 = __builtin_bit_cast(bfx8, *(const s16x8*)(arow));
            const bfx8 a1 = __builtin_bit_cast(bfx8, *(const s16x8*)(arow + 32));
            #pragma unroll
            for (int t = 0; t < 5; ++t) {
                f32x4 acc = {0.f, 0.f, 0.f, 0.f};
                acc = __builtin_amdgcn_mfma_f32_16x16x32_bf16(
                        a0, __builtin_bit_cast(bfx8, bfrag[t][0]), acc, 0, 0, 0);
                acc = __builtin_amdgcn_mfma_f32_16x16x32_bf16(
                        a1, __builtin_bit_cast(bfx8, bfrag[t][1]), acc, 0, 0, 0);
                // lane's 4 acc regs = rows r*16+quad*4+{0..3}: one 4-row group,
                // wholly inside one 24-row segment (24 % 4 == 0)
                const float s = fmaxf(acc[0], 0.f) + fmaxf(acc[1], 0.f)
                              + fmaxf(acc[2], 0.f) + fmaxf(acc[3], 0.f);
                const int g = r * 4 + quad;          // 4-row group 0..11
                const int seg = (g >= 6) ? 1 : 0;
                const int feat = (wave * 5 + t) * 16 + m16;
                atomicAdd(&pooled[seg * K_FEAT + feat], s);
            }
        }
        __syncthreads();

        // logits: 2 segs x 10 classes = 20 outputs; 16 threads each
        const int o = tid >> 4;        // 0..19
        const int part = tid & 15;
        const int seg = (o >= 10) ? 1 : 0;
        const int c = o - seg * 10;
        float sum = 0.f;
        const float* pv = &pooled[seg * K_FEAT + part * 25];
        const float* wv = &w2s[c * K_FEAT + part * 25];
        #pragma unroll
        for (int j = 0; j < 25; ++j) sum += pv[j] * wv[j];
        sum += __shfl_down(sum, 8, 16);
        sum += __shfl_down(sum, 4, 16);
        sum += __shfl_down(sum, 2, 16);
        sum += __shfl_down(sum, 1, 16);
        if (part == 0)
            out[(chunk * 2 + seg) * C_OUT + c] = sum * (1.0f / 24.0f);
    }
}

extern "C" void kernel_launch(void* const* d_in, const int* in_sizes, int n_in,
                              void* d_out, int out_size, void* d_ws, size_t ws_size,
                              hipStream_t stream) {
    const float* x  = (const float*)d_in[0];
    const float* W1 = (const float*)d_in[1];
    const float* W2 = (const float*)d_in[2];
    float* out = (float*)d_out;
    classifier_kernel<<<NBLOCKS, NTHREADS, 0, stream>>>(x, W1, W2, out);
}

// Round 2
// 408.695 us; speedup vs baseline: 1.9029x; 1.9029x over previous
//
#include <hip/hip_runtime.h>
#include <hip/hip_bf16.h>

// Problem constants (fixed by reference)
#define T_TOTAL 786432
#define N_IN 50
#define K_FEAT 400
#define C_OUT 10
#define ROWS_PER_CHUNK 48                      // LCM(16,24): 2 pool segments
#define NCHUNKS (T_TOTAL / ROWS_PER_CHUNK)     // 16384
#define CPB 4                                  // chunks per block
#define NBLOCKS (NCHUNKS / CPB)                // 4096
#define NTHREADS 320                           // 5 waves; each owns 5 of 25 k-tiles
#define XS_STRIDE 72                           // shorts; 144B rows -> <=2-way bank alias on b128
#define XS_ROWS (CPB * ROWS_PER_CHUNK)         // 192

typedef __bf16 bfx8 __attribute__((ext_vector_type(8)));
typedef short  s16x8 __attribute__((ext_vector_type(8)));
typedef float  f32x4 __attribute__((ext_vector_type(4)));

static __device__ __forceinline__ short f2bf(float f) {
    union { float f; unsigned u; } v; v.f = f;
    unsigned r = v.u + 0x7fffu + ((v.u >> 16) & 1u);
    return (short)(r >> 16);
}

__global__ __launch_bounds__(NTHREADS) void classifier_kernel(
    const float* __restrict__ x, const float* __restrict__ W1,
    const float* __restrict__ W2, float* __restrict__ out)
{
    __shared__ short xs[XS_ROWS * XS_STRIDE];   // 27648 B: bf16 x-tile, 4 chunks
    __shared__ float pooled[2 * K_FEAT];        // 3200 B: single writer per addr

    const int tid  = threadIdx.x;
    const int wave = tid >> 6;      // 0..4
    const int lane = tid & 63;
    const int m16  = lane & 15;
    const int quad = lane >> 4;

    // ---- per-thread W2 row (once per block, L2-hot) ----
    const int o    = tid >> 4;             // 0..19
    const int part = tid & 15;
    const int segO = (o >= 10) ? 1 : 0;
    const int cls  = o - segO * 10;
    float w2r[25];
    {
        const float* w2p = W2 + cls * K_FEAT + part * 25;
        #pragma unroll
        for (int j = 0; j < 25; ++j) w2r[j] = w2p[j];
    }

    // ---- B fragments (W1^T) once per wave into registers ----
    // lane holds B[k=quad*8+j][n=m16] = W1[ktile*16+m16][s*32+quad*8+j]
    s16x8 bfrag[5][2];
    #pragma unroll
    for (int t = 0; t < 5; ++t) {
        const int kk = (wave * 5 + t) * 16 + m16;
        const float* w1row = W1 + kk * N_IN;
        // s=0: cols quad*8..quad*8+7, always valid, 8B-aligned -> float2 x4
        {
            s16x8 f;
            const float* p = w1row + quad * 8;
            #pragma unroll
            for (int h = 0; h < 4; ++h) {
                const float2 v = *(const float2*)(p + 2 * h);
                f[2 * h]     = f2bf(v.x);
                f[2 * h + 1] = f2bf(v.y);
            }
            bfrag[t][0] = f;
        }
        // s=1: cols 32+quad*8+j, guard n<50
        {
            s16x8 f;
            #pragma unroll
            for (int j = 0; j < 8; ++j) {
                const int n = 32 + quad * 8 + j;
                f[j] = (n < N_IN) ? f2bf(w1row[n]) : (short)0;
            }
            bfrag[t][1] = f;
        }
    }

    // ---- stage ALL 4 chunks of x -> LDS bf16 (15 float2 per thread) ----
    {
        const float* xb = x + (size_t)blockIdx.x * (XS_ROWS * N_IN);
        #pragma unroll
        for (int it = 0; it < (XS_ROWS * 25) / NTHREADS; ++it) {   // 15 iters
            const int i = tid + it * NTHREADS;                     // i < 4800
            const int r = i / 25;
            const int c2 = i - r * 25;
            const float2 v = *(const float2*)(xb + 2 * i);
            const int packed = (unsigned short)f2bf(v.x) |
                               ((unsigned)(unsigned short)f2bf(v.y) << 16);
            *(int*)&xs[r * XS_STRIDE + 2 * c2] = packed;
        }
        // zero pad cols 50..63 (7 ints per row)
        for (int i = tid; i < XS_ROWS * 7; i += NTHREADS) {
            const int r = i / 7;
            const int c = 50 + 2 * (i - r * 7);
            *(int*)&xs[r * XS_STRIDE + c] = 0;
        }
    }
    __syncthreads();

    for (int ciq = 0; ciq < CPB; ++ciq) {
        // A fragments for the 3 row-tiles of this chunk (all from LDS)
        s16x8 a[3][2];
        #pragma unroll
        for (int r = 0; r < 3; ++r) {
            const short* arow =
                &xs[(ciq * ROWS_PER_CHUNK + r * 16 + m16) * XS_STRIDE + quad * 8];
            a[r][0] = *(const s16x8*)(arow);
            a[r][1] = *(const s16x8*)(arow + 32);
        }

        #pragma unroll
        for (int t = 0; t < 5; ++t) {
            float c0 = 0.f, c1 = 0.f;
            #pragma unroll
            for (int r = 0; r < 3; ++r) {
                f32x4 acc = {0.f, 0.f, 0.f, 0.f};
                acc = __builtin_amdgcn_mfma_f32_16x16x32_bf16(
                        __builtin_bit_cast(bfx8, a[r][0]),
                        __builtin_bit_cast(bfx8, bfrag[t][0]), acc, 0, 0, 0);
                acc = __builtin_amdgcn_mfma_f32_16x16x32_bf16(
                        __builtin_bit_cast(bfx8, a[r][1]),
                        __builtin_bit_cast(bfx8, bfrag[t][1]), acc, 0, 0, 0);
                const float s = fmaxf(acc[0], 0.f) + fmaxf(acc[1], 0.f)
                              + fmaxf(acc[2], 0.f) + fmaxf(acc[3], 0.f);
                // lane's 4 rows = group g = r*4+quad; g<6 -> seg0 else seg1
                const int g = r * 4 + quad;
                if (g < 6) c0 += s; else c1 += s;
            }
            // reduce across the quad dimension (lanes xor 16, 32)
            c0 += __shfl_xor(c0, 16);
            c0 += __shfl_xor(c0, 32);
            c1 += __shfl_xor(c1, 16);
            c1 += __shfl_xor(c1, 32);
            if (quad == 0) {
                const int feat = (wave * 5 + t) * 16 + m16;
                pooled[feat] = c0;
                pooled[K_FEAT + feat] = c1;
            }
        }
        __syncthreads();   // pooled ready

        // logits: 2 segs x 10 classes, 16 partial-threads each
        float sum = 0.f;
        const float* pv = &pooled[segO * K_FEAT + part * 25];
        #pragma unroll
        for (int j = 0; j < 25; ++j) sum += pv[j] * w2r[j];
        sum += __shfl_down(sum, 8, 16);
        sum += __shfl_down(sum, 4, 16);
        sum += __shfl_down(sum, 2, 16);
        sum += __shfl_down(sum, 1, 16);
        if (part == 0) {
            const int chunk = blockIdx.x * CPB + ciq;
            out[(chunk * 2 + segO) * C_OUT + cls] = sum * (1.0f / 24.0f);
        }
        __syncthreads();   // pooled readers done before next chunk's stores
    }
}

extern "C" void kernel_launch(void* const* d_in, const int* in_sizes, int n_in,
                              void* d_out, int out_size, void* d_ws, size_t ws_size,
                              hipStream_t stream) {
    const float* x  = (const float*)d_in[0];
    const float* W1 = (const float*)d_in[1];
    const float* W2 = (const float*)d_in[2];
    float* out = (float*)d_out;
    classifier_kernel<<<NBLOCKS, NTHREADS, 0, stream>>>(x, W1, W2, out);
}

// Round 3
// 287.953 us; speedup vs baseline: 2.7008x; 1.4193x over previous
//
#include <hip/hip_runtime.h>
#include <hip/hip_bf16.h>

// Problem constants (fixed by reference)
#define T_TOTAL 786432
#define N_IN 50
#define K_FEAT 400
#define C_OUT 10
#define ROWS_PER_CHUNK 48                      // LCM(16,24): 2 pool segments
#define NCHUNKS (T_TOTAL / ROWS_PER_CHUNK)     // 16384
#define CPB 4                                  // chunks per block
#define NBLOCKS (NCHUNKS / CPB)                // 4096
#define NTHREADS 320                           // 5 waves; each owns 5 of 25 k-tiles
#define XS_STRIDE 72                           // shorts; 144B rows -> <=2-way bank alias on b128
#define XS_ROWS (CPB * ROWS_PER_CHUNK)         // 192

// Workspace layout (d_ws):
//   [0, 51200)        : W1 fragments, bf16 shorts. For tile (0..24), kstep s (0..1),
//                       lane (0..63): 8 shorts at ((tile*2+s)*64+lane)*8.
//   [51200, 83200)    : W2 transposed floats: w2t[j*320 + tid], j in 0..24.
#define W1F_TASKS (25 * 2 * 64)        // 3200, each task writes 8 shorts (16 B)
#define W2T_OFF_BYTES 51200
#define W2T_FLOATS (25 * NTHREADS)     // 8000
#define PREP_TASKS (W1F_TASKS + W2T_FLOATS)

typedef __bf16 bfx8 __attribute__((ext_vector_type(8)));
typedef short  s16x8 __attribute__((ext_vector_type(8)));
typedef float  f32x4 __attribute__((ext_vector_type(4)));

static __device__ __forceinline__ short f2bf(float f) {
    union { float f; unsigned u; } v; v.f = f;
    unsigned r = v.u + 0x7fffu + ((v.u >> 16) & 1u);
    return (short)(r >> 16);
}

__global__ void prep_kernel(const float* __restrict__ W1,
                            const float* __restrict__ W2,
                            short* __restrict__ w1f, float* __restrict__ w2t)
{
    const int gid = blockIdx.x * blockDim.x + threadIdx.x;
    if (gid < W1F_TASKS) {
        // one MFMA B-fragment (8 shorts) per task
        const int lane = gid & 63;
        const int s    = (gid >> 6) & 1;
        const int tile = gid >> 7;          // 0..24
        const int m16  = lane & 15;
        const int quad = lane >> 4;
        const float* row = W1 + (tile * 16 + m16) * N_IN;
        s16x8 v;
        #pragma unroll
        for (int j = 0; j < 8; ++j) {
            const int n = s * 32 + quad * 8 + j;
            v[j] = (n < N_IN) ? f2bf(row[n]) : (short)0;
        }
        *(s16x8*)&w1f[gid * 8] = v;
    } else if (gid < PREP_TASKS) {
        const int i   = gid - W1F_TASKS;    // i = j*320 + tid
        const int j   = i / NTHREADS;
        const int tid = i - j * NTHREADS;
        const int o    = tid >> 4;
        const int part = tid & 15;
        const int seg  = (o >= 10) ? 1 : 0;
        const int cls  = o - seg * 10;
        w2t[i] = W2[cls * K_FEAT + part * 25 + j];
    }
}

__global__ __launch_bounds__(NTHREADS) void classifier_kernel(
    const float* __restrict__ x, const short* __restrict__ w1f,
    const float* __restrict__ w2t, float* __restrict__ out)
{
    __shared__ short xs[XS_ROWS * XS_STRIDE];   // 27648 B: bf16 x-tile, 4 chunks
    __shared__ float pooled[2 * K_FEAT];        // 3200 B: single writer per addr

    const int tid  = threadIdx.x;
    const int wave = tid >> 6;      // 0..4
    const int lane = tid & 63;
    const int m16  = lane & 15;
    const int quad = lane >> 4;

    // ---- stage ALL 4 chunks of x -> LDS bf16 (15 float2 per thread) ----
    // issued first: longest-latency HBM stream
    {
        const float* xb = x + (size_t)blockIdx.x * (XS_ROWS * N_IN);
        #pragma unroll
        for (int it = 0; it < (XS_ROWS * 25) / NTHREADS; ++it) {   // 15 iters
            const int i = tid + it * NTHREADS;                     // i < 4800
            const int r = i / 25;
            const int c2 = i - r * 25;
            const float2 v = *(const float2*)(xb + 2 * i);
            const int packed = (unsigned short)f2bf(v.x) |
                               ((unsigned)(unsigned short)f2bf(v.y) << 16);
            *(int*)&xs[r * XS_STRIDE + 2 * c2] = packed;
        }
        // zero pad cols 50..63 (7 ints per row)
        for (int i = tid; i < XS_ROWS * 7; i += NTHREADS) {
            const int r = i / 7;
            const int c = 50 + 2 * (i - r * 7);
            *(int*)&xs[r * XS_STRIDE + c] = 0;
        }
    }

    // ---- B fragments: 10 coalesced dwordx4 loads per lane (L2/L3-hot) ----
    s16x8 bfrag[5][2];
    {
        const s16x8* wf = (const s16x8*)w1f;
        #pragma unroll
        for (int t = 0; t < 5; ++t) {
            #pragma unroll
            for (int s = 0; s < 2; ++s)
                bfrag[t][s] = wf[((wave * 5 + t) * 2 + s) * 64 + lane];
        }
    }

    // ---- W2 row: 25 coalesced dword loads ----
    const int o    = tid >> 4;             // 0..19
    const int part = tid & 15;
    const int segO = (o >= 10) ? 1 : 0;
    const int cls  = o - segO * 10;
    float w2r[25];
    #pragma unroll
    for (int j = 0; j < 25; ++j) w2r[j] = w2t[j * NTHREADS + tid];

    __syncthreads();

    for (int ciq = 0; ciq < CPB; ++ciq) {
        // A fragments for the 3 row-tiles of this chunk (all from LDS)
        s16x8 a[3][2];
        #pragma unroll
        for (int r = 0; r < 3; ++r) {
            const short* arow =
                &xs[(ciq * ROWS_PER_CHUNK + r * 16 + m16) * XS_STRIDE + quad * 8];
            a[r][0] = *(const s16x8*)(arow);
            a[r][1] = *(const s16x8*)(arow + 32);
        }

        #pragma unroll
        for (int t = 0; t < 5; ++t) {
            float c0 = 0.f, c1 = 0.f;
            #pragma unroll
            for (int r = 0; r < 3; ++r) {
                f32x4 acc = {0.f, 0.f, 0.f, 0.f};
                acc = __builtin_amdgcn_mfma_f32_16x16x32_bf16(
                        __builtin_bit_cast(bfx8, a[r][0]),
                        __builtin_bit_cast(bfx8, bfrag[t][0]), acc, 0, 0, 0);
                acc = __builtin_amdgcn_mfma_f32_16x16x32_bf16(
                        __builtin_bit_cast(bfx8, a[r][1]),
                        __builtin_bit_cast(bfx8, bfrag[t][1]), acc, 0, 0, 0);
                const float s = fmaxf(acc[0], 0.f) + fmaxf(acc[1], 0.f)
                              + fmaxf(acc[2], 0.f) + fmaxf(acc[3], 0.f);
                // lane's 4 rows = group g = r*4+quad; g<6 -> seg0 else seg1
                const int g = r * 4 + quad;
                if (g < 6) c0 += s; else c1 += s;
            }
            // reduce across the quad dimension (lanes xor 16, 32)
            c0 += __shfl_xor(c0, 16);
            c0 += __shfl_xor(c0, 32);
            c1 += __shfl_xor(c1, 16);
            c1 += __shfl_xor(c1, 32);
            if (quad == 0) {
                const int feat = (wave * 5 + t) * 16 + m16;
                pooled[feat] = c0;
                pooled[K_FEAT + feat] = c1;
            }
        }
        __syncthreads();   // pooled ready

        // logits: 2 segs x 10 classes, 16 partial-threads each
        float sum = 0.f;
        const float* pv = &pooled[segO * K_FEAT + part * 25];
        #pragma unroll
        for (int j = 0; j < 25; ++j) sum += pv[j] * w2r[j];
        sum += __shfl_down(sum, 8, 16);
        sum += __shfl_down(sum, 4, 16);
        sum += __shfl_down(sum, 2, 16);
        sum += __shfl_down(sum, 1, 16);
        if (part == 0) {
            const int chunk = blockIdx.x * CPB + ciq;
            out[(chunk * 2 + segO) * C_OUT + cls] = sum * (1.0f / 24.0f);
        }
        __syncthreads();   // pooled readers done before next chunk's stores
    }
}

extern "C" void kernel_launch(void* const* d_in, const int* in_sizes, int n_in,
                              void* d_out, int out_size, void* d_ws, size_t ws_size,
                              hipStream_t stream) {
    const float* x  = (const float*)d_in[0];
    const float* W1 = (const float*)d_in[1];
    const float* W2 = (const float*)d_in[2];
    float* out = (float*)d_out;

    short* w1f = (short*)d_ws;
    float* w2t = (float*)((char*)d_ws + W2T_OFF_BYTES);

    prep_kernel<<<(PREP_TASKS + 255) / 256, 256, 0, stream>>>(W1, W2, w1f, w2t);
    classifier_kernel<<<NBLOCKS, NTHREADS, 0, stream>>>(x, w1f, w2t, out);
}